// Round 4
// baseline (499.010 us; speedup 1.0000x reference)
//
#include <hip/hip_runtime.h>
#include <math.h>

#define N_NODES 20000
#define N_EDGES 320000

typedef __attribute__((ext_vector_type(8))) __bf16 bf16x8;
typedef __attribute__((ext_vector_type(8))) unsigned short ushort8;
typedef __attribute__((ext_vector_type(4))) float floatx4;

// ---- fp32 -> bf16 (RNE) raw bits ----
__device__ __forceinline__ unsigned short f2b(float f) {
    unsigned int u = __float_as_uint(f);
    unsigned int r = (u + 0x7fffu + ((u >> 16) & 1u)) >> 16;
    return (unsigned short)r;
}
// ---- bf16 bits -> fp32 ----
__device__ __forceinline__ float b2f(unsigned short u) {
    return __uint_as_float(((unsigned int)u) << 16);
}

// ---- in_proj: h0[N,32] = x[N,18] @ W[18,32] + b  (bf16 out) ----
__global__ void k_inproj(const float* __restrict__ x, const float* __restrict__ W,
                         const float* __restrict__ b, unsigned short* __restrict__ h0) {
    int t = blockIdx.x * blockDim.x + threadIdx.x;
    if (t >= N_NODES * 32) return;
    int n = t >> 5, p = t & 31;
    float acc = b[p];
    const float* xr = x + n * 18;
#pragma unroll
    for (int k = 0; k < 18; k++) acc = fmaf(xr[k], W[k * 32 + p], acc);
    h0[t] = f2b(acc);
}

// ---- merged weight convert+transpose: all 7 weights in one launch ----
// W[K][N] fp32 -> Wt[N][K] bf16.
// For the K=256 weights (used by the LDS-resident GEMM) the within-row k-chunks
// are XOR-swizzled (chunk' = chunk ^ (n&7), chunk = 16B = 8 bf16) so the GEMM
// can stage LDS with a pure linear copy and read fragments conflict-free.
// W_cls is padded to 1024 cols (zeros) so the N=1000 GEMM needs no stage guards.
__global__ void k_wcvt_all(const float* __restrict__ Wl1, const float* __restrict__ Wr1,
                           const float* __restrict__ Wdn, const float* __restrict__ Wl2,
                           const float* __restrict__ Wr2, const float* __restrict__ Wup,
                           const float* __restrict__ Wcl,
                           unsigned short* __restrict__ o1, unsigned short* __restrict__ o2,
                           unsigned short* __restrict__ o3, unsigned short* __restrict__ o4,
                           unsigned short* __restrict__ o5, unsigned short* __restrict__ o6,
                           unsigned short* __restrict__ o7) {
    int t = blockIdx.x * blockDim.x + threadIdx.x;
    const float* W; unsigned short* O; int Nd, K, idx; bool swz;
    if (t < 8192)        { W = Wl1; O = o1; Nd = 256;  K = 32;  idx = t;          swz = false; }
    else if (t < 16384)  { W = Wr1; O = o2; Nd = 256;  K = 32;  idx = t - 8192;   swz = false; }
    else if (t < 81920)  { W = Wdn; O = o3; Nd = 256;  K = 256; idx = t - 16384;  swz = true; }
    else if (t < 147456) { W = Wl2; O = o4; Nd = 256;  K = 256; idx = t - 81920;  swz = true; }
    else if (t < 212992) { W = Wr2; O = o5; Nd = 256;  K = 256; idx = t - 147456; swz = true; }
    else if (t < 278528) { W = Wup; O = o6; Nd = 256;  K = 256; idx = t - 212992; swz = true; }
    else if (t < 540672) { W = Wcl; O = o7; Nd = 1000; K = 256; idx = t - 278528; swz = true; }
    else return;
    int n = idx / K, k = idx % K;
    float v = (n < Nd) ? W[(size_t)k * Nd + n] : 0.f;   // pad rows -> 0
    int pos = swz ? (n * K + ((((k >> 3) ^ (n & 7)) << 3) | (k & 7))) : idx;
    O[pos] = f2b(v);
}

// ---- bf16 MFMA GEMM (generic, reg-staged): C[M,N] = A[M,K] @ Bt[N,K]^T
// kept only for the K=32 in-proj GEMM.
__global__ __launch_bounds__(256) void k_gemm_bf16(
    const unsigned short* __restrict__ A, const unsigned short* __restrict__ Bt,
    float* __restrict__ Cf, unsigned short* __restrict__ Cb,
    const float* __restrict__ bias, int M, int N, int K) {
    __shared__ unsigned short As[8 * 64 * 8];
    __shared__ unsigned short Bs[8 * 64 * 8];
    int tid = threadIdx.x;
    int wave = tid >> 6, lane = tid & 63;
    int wr = wave >> 1, wc = wave & 1;
    int row0 = blockIdx.x * 128, col0 = blockIdx.y * 128;
    floatx4 zero4 = {0.f, 0.f, 0.f, 0.f};
    floatx4 acc[4][4];
#pragma unroll
    for (int i = 0; i < 4; i++)
#pragma unroll
        for (int j = 0; j < 4; j++) acc[i][j] = zero4;
    for (int kb = 0; kb < K; kb += 32) {
#pragma unroll
        for (int q = 0; q < 2; q++) {
            int c = tid * 2 + q;           // 0..511
            int row = c >> 2, koff = (c & 3) * 8;
            int lp = (row & 15) + 16 * (koff >> 3);
            int mt = row >> 4;
            ushort8 va = {0, 0, 0, 0, 0, 0, 0, 0};
            if (row0 + row < M)
                va = *(const ushort8*)(A + (size_t)(row0 + row) * K + kb + koff);
            *(ushort8*)(As + (mt * 64 + lp) * 8) = va;
            ushort8 vb = {0, 0, 0, 0, 0, 0, 0, 0};
            if (col0 + row < N)
                vb = *(const ushort8*)(Bt + (size_t)(col0 + row) * K + kb + koff);
            *(ushort8*)(Bs + (mt * 64 + lp) * 8) = vb;
        }
        __syncthreads();
        bf16x8 af[4], bfr[4];
#pragma unroll
        for (int i = 0; i < 4; i++)
            af[i] = *(const bf16x8*)(As + ((wr * 4 + i) * 64 + lane) * 8);
#pragma unroll
        for (int j = 0; j < 4; j++)
            bfr[j] = *(const bf16x8*)(Bs + ((wc * 4 + j) * 64 + lane) * 8);
#pragma unroll
        for (int i = 0; i < 4; i++)
#pragma unroll
            for (int j = 0; j < 4; j++)
                acc[i][j] = __builtin_amdgcn_mfma_f32_16x16x32_bf16(
                    af[i], bfr[j], acc[i][j], 0, 0, 0);
        __syncthreads();
    }
    int quad = lane >> 4, nl = lane & 15;
#pragma unroll
    for (int i = 0; i < 4; i++) {
#pragma unroll
        for (int j = 0; j < 4; j++) {
            int col = col0 + wc * 64 + j * 16 + nl;
            if (col >= N) continue;
            float bv = bias ? bias[col] : 0.f;
#pragma unroll
            for (int r = 0; r < 4; r++) {
                int rr = row0 + wr * 64 + i * 16 + quad * 4 + r;
                if (rr >= M) continue;
                float v = acc[i][j][r] + bv;
                if (Cf) Cf[(size_t)rr * N + col] = v;
                else Cb[(size_t)rr * N + col] = f2b(v);
            }
        }
    }
}

// ---- K=256 GEMM with LDS-resident B panel + optional fused LayerNorm ----
// Tile: 128 rows x 256 cols per block (4 waves 2x2, wave = 64x128).
// B-panel [256 cols][256 k] bf16 = 128 KB staged ONCE into LDS (linear copy of
// the pre-swizzled weight image); the K-loop then runs with ZERO barriers:
// A fragments are loaded straight from global into VGPRs, prefetched 1 K-step
// ahead; B fragments come from LDS (XOR-swizzled -> ~conflict-free b128 reads).
// Epilogue: optional bias, or fused LayerNorm (with optional fp32 residual).
__global__ __launch_bounds__(256, 1) void k_gemm_ln(
    const unsigned short* __restrict__ A,    // [M][256] bf16
    const unsigned short* __restrict__ Bsw,  // [Npad][256] bf16, chunk-swizzled
    int M, int Ncols, int ldC,
    const float* __restrict__ bias,          // per-col bias or null
    const float* __restrict__ res,           // [M][256] fp32 residual (LN only) or null
    const float* __restrict__ g, const float* __restrict__ b,  // LN params or null
    float* __restrict__ outf, unsigned short* __restrict__ outb) {
    __shared__ unsigned short Bs[256 * 256];   // 128 KB B panel
    __shared__ float red[2][128][2];           // per-row (sum, sumsq) partials per wc
    int tid = threadIdx.x, lane = tid & 63, wave = tid >> 6;
    int wr = wave >> 1, wc = wave & 1;
    int nl = lane & 15, quad = lane >> 4;
    int row0 = blockIdx.x * 128, col0 = blockIdx.y * 256;

    // A fragment base: lane covers row (l&15), k-chunk (l>>4)*8 of each 16x32 frag
    const unsigned short* aptr =
        A + (size_t)(row0 + wr * 64 + nl) * 256 + quad * 8;
    // issue first K-step's A frags before staging (overlaps with B copy)
    bf16x8 a_cur[4], a_nxt[4];
#pragma unroll
    for (int i = 0; i < 4; i++) {
        a_cur[i] = *(const bf16x8*)(aptr + i * 16 * 256);
        a_nxt[i] = a_cur[i];
    }

    // stage B panel: linear 128 KB copy, perfectly coalesced
    // (panel = 256*256 ushort = 8192 ushort8; 256 threads -> 32 iterations)
    {
        const ushort8* bsrc8 = (const ushort8*)(Bsw + (size_t)col0 * 256);
        ushort8* bdst8 = (ushort8*)Bs;
#pragma unroll
        for (int t = 0; t < 32; t++) bdst8[t * 256 + tid] = bsrc8[t * 256 + tid];
    }
    __syncthreads();

    floatx4 zero4 = {0.f, 0.f, 0.f, 0.f};
    floatx4 acc[4][8];
#pragma unroll
    for (int i = 0; i < 4; i++)
#pragma unroll
        for (int j = 0; j < 8; j++) acc[i][j] = zero4;

    int lcbase = wc * 128 + nl;       // local B col for this lane (low bits -> swizzle)
    int swx = lcbase & 7;
#pragma unroll
    for (int kb = 0; kb < 8; kb++) {
        if (kb < 7) {
#pragma unroll
            for (int i = 0; i < 4; i++)
                a_nxt[i] = *(const bf16x8*)(aptr + i * 16 * 256 + (kb + 1) * 32);
        }
        int swz_byte = (((kb * 4 + quad) ^ swx) << 4);   // swizzled 16B chunk offset
#pragma unroll
        for (int j = 0; j < 8; j++) {
            bf16x8 bf = *(const bf16x8*)((const char*)Bs +
                                         (size_t)(lcbase + j * 16) * 512 + swz_byte);
#pragma unroll
            for (int i = 0; i < 4; i++)
                acc[i][j] = __builtin_amdgcn_mfma_f32_16x16x32_bf16(
                    a_cur[i], bf, acc[i][j], 0, 0, 0);
        }
#pragma unroll
        for (int i = 0; i < 4; i++) a_cur[i] = a_nxt[i];
    }

    if (g == nullptr) {
        // plain epilogue: optional bias, guarded stores
#pragma unroll
        for (int j = 0; j < 8; j++) {
            int col = col0 + wc * 128 + j * 16 + nl;
            if (col >= Ncols) continue;
            float bv = bias ? bias[col] : 0.f;
#pragma unroll
            for (int i = 0; i < 4; i++) {
#pragma unroll
                for (int r = 0; r < 4; r++) {
                    int rr = row0 + wr * 64 + i * 16 + quad * 4 + r;
                    if (rr >= M) continue;
                    float v = acc[i][j][r] + bv;
                    if (outf) outf[(size_t)rr * ldC + col] = v;
                    if (outb) outb[(size_t)rr * ldC + col] = f2b(v);
                }
            }
        }
        return;
    }

    // ---- fused LayerNorm epilogue (Ncols == 256, ldC == 256) ----
    if (res) {
#pragma unroll
        for (int i = 0; i < 4; i++)
#pragma unroll
            for (int j = 0; j < 8; j++) {
                int col = wc * 128 + j * 16 + nl;
#pragma unroll
                for (int r = 0; r < 4; r++) {
                    int rr = row0 + wr * 64 + i * 16 + quad * 4 + r;
                    acc[i][j][r] += res[(size_t)rr * 256 + col];
                }
            }
    }
    // per-row partial sum/sumsq over this wave's 128 cols
#pragma unroll
    for (int i = 0; i < 4; i++) {
#pragma unroll
        for (int r = 0; r < 4; r++) {
            float s = 0.f, q = 0.f;
#pragma unroll
            for (int j = 0; j < 8; j++) {
                float v = acc[i][j][r];
                s += v;
                q = fmaf(v, v, q);
            }
            s += __shfl_xor(s, 1, 64); q += __shfl_xor(q, 1, 64);
            s += __shfl_xor(s, 2, 64); q += __shfl_xor(q, 2, 64);
            s += __shfl_xor(s, 4, 64); q += __shfl_xor(q, 4, 64);
            s += __shfl_xor(s, 8, 64); q += __shfl_xor(q, 8, 64);
            if (nl == 0) {
                int lr = wr * 64 + i * 16 + quad * 4 + r;
                red[wc][lr][0] = s;
                red[wc][lr][1] = q;
            }
        }
    }
    __syncthreads();
    float mean_[4][4], rstd_[4][4];
#pragma unroll
    for (int i = 0; i < 4; i++) {
#pragma unroll
        for (int r = 0; r < 4; r++) {
            int lr = wr * 64 + i * 16 + quad * 4 + r;
            float sum = red[0][lr][0] + red[1][lr][0];
            float sq = red[0][lr][1] + red[1][lr][1];
            float mean = sum * (1.0f / 256.0f);
            float var = sq * (1.0f / 256.0f) - mean * mean;
            mean_[i][r] = mean;
            rstd_[i][r] = 1.0f / sqrtf(var + 1e-5f);
        }
    }
#pragma unroll
    for (int j = 0; j < 8; j++) {
        int col = wc * 128 + j * 16 + nl;
        float gv = g[col], bvv = b[col];
#pragma unroll
        for (int i = 0; i < 4; i++) {
#pragma unroll
            for (int r = 0; r < 4; r++) {
                int rr = row0 + wr * 64 + i * 16 + quad * 4 + r;
                if (rr >= M) continue;
                float o = (acc[i][j][r] - mean_[i][r]) * rstd_[i][r] * gv + bvv;
                if (outf) outf[(size_t)rr * 256 + col] = o;
                if (outb) outb[(size_t)rr * 256 + col] = f2b(o);
            }
        }
    }
}

// ---- CSR build: histogram of dst ----
__global__ void k_hist(const int* __restrict__ dst, int* __restrict__ cnt) {
    int e = blockIdx.x * blockDim.x + threadIdx.x;
    if (e >= N_EDGES) return;
    atomicAdd(cnt + dst[e], 1);
}

// ---- CSR build: fast single-block scan (1024 threads, 20 elems/thread) ----
__global__ __launch_bounds__(1024) void k_scan(const int* __restrict__ cnt,
                                               int* __restrict__ rowptr,
                                               int* __restrict__ wp, int n) {
    __shared__ int tsum[1024];
    int t = threadIdx.x;
    const int chunk = 20;  // 1024*20 = 20480 >= 20000
    int i0 = t * chunk;
    int local[chunk];
    int s = 0;
#pragma unroll
    for (int j = 0; j < chunk; j++) {
        int i = i0 + j;
        int v = (i < n) ? cnt[i] : 0;
        local[j] = s;  // exclusive prefix within chunk
        s += v;
    }
    tsum[t] = s;
    __syncthreads();
    // inclusive Hillis-Steele scan over 1024 partials
    for (int off = 1; off < 1024; off <<= 1) {
        int other = (t >= off) ? tsum[t - off] : 0;
        __syncthreads();
        tsum[t] += other;
        __syncthreads();
    }
    int base = (t > 0) ? tsum[t - 1] : 0;
#pragma unroll
    for (int j = 0; j < chunk; j++) {
        int i = i0 + j;
        if (i < n) {
            int ex = base + local[j];
            rowptr[i] = ex;
            wp[i] = ex;
        }
    }
    if (t == 1023) rowptr[n] = tsum[1023];
}

// ---- CSR build: scatter src id + edge attr into CSR order ----
__global__ void k_fill(const int* __restrict__ src, const int* __restrict__ dst,
                       const float* __restrict__ ea, int* __restrict__ wp,
                       int* __restrict__ srcs, float* __restrict__ eas) {
    int e = blockIdx.x * blockDim.x + threadIdx.x;
    if (e >= N_EDGES) return;
    int p = atomicAdd(wp + dst[e], 1);
    srcs[p] = src[e];
    eas[p] = ea[e];
}

// ---- fused GATv2 edge phase + LayerNorm epilogue
// wave per dst node, online softmax, 2 edges/iteration.
// Edge metadata (srcs/eas) is CSR-ordered -> sequential loads, no indirection.
// Row gathers are kept 3 pairs (6 edges) in flight to cover LLC/HBM latency.
// xlr: [N][512] bf16 where cols 0..255 = x@Wl, 256..511 = x@Wr
// epilogue: o = agg + vbias (+res) ; LN(o; g,b) -> outf (fp32) / outb (bf16)
__global__ __launch_bounds__(256) void k_gat_ln(
    const int* __restrict__ rowptr, const int* __restrict__ srcs,
    const float* __restrict__ eas, const unsigned short* __restrict__ xlr,
    const float* __restrict__ We, const float* __restrict__ att,
    const float* __restrict__ vbias, const float* __restrict__ res,
    const float* __restrict__ g, const float* __restrict__ b,
    float* __restrict__ outf, unsigned short* __restrict__ outb) {
    int node = blockIdx.x * 4 + (threadIdx.x >> 6);
    if (node >= N_NODES) return;
    int lane = threadIdx.x & 63;  // lane covers dims [4*lane, 4*lane+4)
    int beg = rowptr[node], end = rowptr[node + 1];
    float4 wv = ((const float4*)We)[lane];
    float4 av = ((const float4*)att)[lane];
    ushort4 xru = ((const ushort4*)(xlr + (size_t)node * 512 + 256))[lane];
    float4 rv = make_float4(b2f(xru.x), b2f(xru.y), b2f(xru.z), b2f(xru.w));
    float m = -3.0e38f, l = 0.f;
    float4 acc = make_float4(0.f, 0.f, 0.f, 0.f);
    if (beg < end) {
        int last = end - 1;
        int i1 = (beg + 1 < end) ? beg + 1 : last;
        int i2 = (beg + 2 < end) ? beg + 2 : last;
        int i3 = (beg + 3 < end) ? beg + 3 : last;
        int i4 = (beg + 4 < end) ? beg + 4 : last;
        int i5 = (beg + 5 < end) ? beg + 5 : last;
        int i6 = (beg + 6 < end) ? beg + 6 : last;
        int i7 = (beg + 7 < end) ? beg + 7 : last;
        int s0a = srcs[beg], s0b = srcs[i1];
        int s1a = srcs[i2],  s1b = srcs[i3];
        int s2a = srcs[i4],  s2b = srcs[i5];
        int s3a = srcs[i6],  s3b = srcs[i7];
        float a0a = eas[beg], a0b = eas[i1];
        float a1a = eas[i2],  a1b = eas[i3];
        float a2a = eas[i4],  a2b = eas[i5];
        float a3a = eas[i6],  a3b = eas[i7];
        ushort4 x0a = ((const ushort4*)(xlr + (size_t)s0a * 512))[lane];
        ushort4 x0b = ((const ushort4*)(xlr + (size_t)s0b * 512))[lane];
        ushort4 x1a = ((const ushort4*)(xlr + (size_t)s1a * 512))[lane];
        ushort4 x1b = ((const ushort4*)(xlr + (size_t)s1b * 512))[lane];
        ushort4 x2a = ((const ushort4*)(xlr + (size_t)s2a * 512))[lane];
        ushort4 x2b = ((const ushort4*)(xlr + (size_t)s2b * 512))[lane];
        for (int i = beg; i < end; i += 2) {
            int j8 = (i + 8 < end) ? i + 8 : last;
            int j9 = (i + 9 < end) ? i + 9 : last;
            int s4a = srcs[j8], s4b = srcs[j9];
            float a4a = eas[j8], a4b = eas[j9];
            ushort4 x3a = ((const ushort4*)(xlr + (size_t)s3a * 512))[lane];
            ushort4 x3b = ((const ushort4*)(xlr + (size_t)s3b * 512))[lane];
            float4 lva = make_float4(b2f(x0a.x), b2f(x0a.y), b2f(x0a.z), b2f(x0a.w));
            float4 lvb = make_float4(b2f(x0b.x), b2f(x0b.y), b2f(x0b.z), b2f(x0b.w));
            float f, pa = 0.f, pb = 0.f;
            f = lva.x + rv.x + a0a * wv.x; f = fmaxf(f, 0.2f * f); pa = fmaf(f, av.x, pa);
            f = lva.y + rv.y + a0a * wv.y; f = fmaxf(f, 0.2f * f); pa = fmaf(f, av.y, pa);
            f = lva.z + rv.z + a0a * wv.z; f = fmaxf(f, 0.2f * f); pa = fmaf(f, av.z, pa);
            f = lva.w + rv.w + a0a * wv.w; f = fmaxf(f, 0.2f * f); pa = fmaf(f, av.w, pa);
            f = lvb.x + rv.x + a0b * wv.x; f = fmaxf(f, 0.2f * f); pb = fmaf(f, av.x, pb);
            f = lvb.y + rv.y + a0b * wv.y; f = fmaxf(f, 0.2f * f); pb = fmaf(f, av.y, pb);
            f = lvb.z + rv.z + a0b * wv.z; f = fmaxf(f, 0.2f * f); pb = fmaf(f, av.z, pb);
            f = lvb.w + rv.w + a0b * wv.w; f = fmaxf(f, 0.2f * f); pb = fmaf(f, av.w, pb);
            pa += __shfl_xor(pa, 1, 64);
            pa += __shfl_xor(pa, 2, 64);
            pa += __shfl_xor(pa, 4, 64);
            pb += __shfl_xor(pb, 1, 64);
            pb += __shfl_xor(pb, 2, 64);
            pb += __shfl_xor(pb, 4, 64);
            if (i + 1 >= end) pb = -3.0e38f;  // odd tail: second edge is a dummy
            float mnew = fmaxf(fmaxf(m, pa), pb);
            float scale = __expf(m - mnew);
            float wa = __expf(pa - mnew);
            float wb = __expf(pb - mnew);
            acc.x = fmaf(acc.x, scale, fmaf(wa, lva.x, wb * lvb.x));
            acc.y = fmaf(acc.y, scale, fmaf(wa, lva.y, wb * lvb.y));
            acc.z = fmaf(acc.z, scale, fmaf(wa, lva.z, wb * lvb.z));
            acc.w = fmaf(acc.w, scale, fmaf(wa, lva.w, wb * lvb.w));
            l = fmaf(l, scale, wa + wb);
            m = mnew;
            x0a = x1a; x0b = x1b; x1a = x2a; x1b = x2b; x2a = x3a; x2b = x3b;
            a0a = a1a; a0b = a1b; a1a = a2a; a1b = a2b; a2a = a3a; a2b = a3b;
            a3a = a4a; a3b = a4b; s3a = s4a; s3b = s4b;
        }
    }
    float inv = 1.0f / (l + 1e-16f);
    float4 vb4 = ((const float4*)vbias)[lane];
    float4 o = make_float4(fmaf(acc.x, inv, vb4.x), fmaf(acc.y, inv, vb4.y),
                           fmaf(acc.z, inv, vb4.z), fmaf(acc.w, inv, vb4.w));
    if (res) {
        float4 r4 = ((const float4*)(res + (size_t)node * 256))[lane];
        o.x += r4.x; o.y += r4.y; o.z += r4.z; o.w += r4.w;
    }
    float sum = o.x + o.y + o.z + o.w;
#pragma unroll
    for (int off = 32; off > 0; off >>= 1) sum += __shfl_xor(sum, off, 64);
    float mean = sum * (1.0f / 256.0f);
    float dx = o.x - mean, dy = o.y - mean, dz = o.z - mean, dw = o.w - mean;
    float sq = dx * dx + dy * dy + dz * dz + dw * dw;
#pragma unroll
    for (int off = 32; off > 0; off >>= 1) sq += __shfl_xor(sq, off, 64);
    float rstd = 1.0f / sqrtf(sq * (1.0f / 256.0f) + 1e-5f);
    float4 gg = ((const float4*)g)[lane];
    float4 bb = ((const float4*)b)[lane];
    float4 o4 = make_float4(dx * rstd * gg.x + bb.x, dy * rstd * gg.y + bb.y,
                            dz * rstd * gg.z + bb.z, dw * rstd * gg.w + bb.w);
    if (outf) ((float4*)(outf + (size_t)node * 256))[lane] = o4;
    if (outb) {
        ushort4 u;
        u.x = f2b(o4.x); u.y = f2b(o4.y); u.z = f2b(o4.z); u.w = f2b(o4.w);
        ((ushort4*)(outb + (size_t)node * 256))[lane] = u;
    }
}

extern "C" void kernel_launch(void* const* d_in, const int* in_sizes, int n_in,
                              void* d_out, int out_size, void* d_ws, size_t ws_size,
                              hipStream_t stream) {
    const float* x_gnn = (const float*)d_in[0];
    const int* ei = (const int*)d_in[1];
    const int* src = ei;
    const int* dst = ei + N_EDGES;
    const float* ea   = (const float*)d_in[2];
    const float* W_in = (const float*)d_in[3];
    const float* b_in = (const float*)d_in[4];
    const float* Wl1  = (const float*)d_in[5];
    const float* Wr1  = (const float*)d_in[6];
    const float* We1  = (const float*)d_in[7];
    const float* att1 = (const float*)d_in[8];
    const float* bg1  = (const float*)d_in[9];
    const float* ln1_g = (const float*)d_in[10];
    const float* ln1_b = (const float*)d_in[11];
    const float* W_down = (const float*)d_in[12];
    const float* lnd_g = (const float*)d_in[13];
    const float* lnd_b = (const float*)d_in[14];
    const float* Wl2  = (const float*)d_in[15];
    const float* Wr2  = (const float*)d_in[16];
    const float* We2  = (const float*)d_in[17];
    const float* att2 = (const float*)d_in[18];
    const float* bg2  = (const float*)d_in[19];
    const float* ln2_g = (const float*)d_in[20];
    const float* ln2_b = (const float*)d_in[21];
    const float* W_up = (const float*)d_in[22];
    const float* lnu_g = (const float*)d_in[23];
    const float* lnu_b = (const float*)d_in[24];
    const float* W_cls = (const float*)d_in[25];
    const float* b_cls = (const float*)d_in[26];

    // ---- workspace layout ----
    float* ws = (float*)d_ws;
    float* B_agg = ws;                                // 5,120,000 f (unused, kept for layout)
    float* B_h1  = B_agg + 5120000;                   // 5,120,000 f
    float* B_z   = B_h1 + 5120000;                    // 5,120,000 f
    unsigned short* B_xlr = (unsigned short*)(B_z + 5120000);  // 10,240,000 us ([N][512])
    unsigned short* B_actb = B_xlr + 10240000;                 // 5,120,000 us
    unsigned short* B_h0b = B_actb + 5120000;                  // 640,000 us
    unsigned short* Wt_l1 = B_h0b + 640000;                    // 8,192  ([512][32] with Wt_r1)
    unsigned short* Wt_r1 = Wt_l1 + 8192;                      // 8,192
    unsigned short* Wt_down = Wt_r1 + 8192;                    // 65,536 (swizzled)
    unsigned short* Wt_l2 = Wt_down + 65536;                   // ([512][256] with Wt_r2, swz)
    unsigned short* Wt_r2 = Wt_l2 + 65536;
    unsigned short* Wt_up = Wt_r2 + 65536;                     // 65,536 (swz)
    unsigned short* Wt_cls = Wt_up + 65536;                    // 262,144 ([1024][256], swz, pad)
    int* C_cnt = (int*)(Wt_cls + 262144);                      // 20,000
    int* C_row = C_cnt + 20000;                                // 20,001
    int* C_wp  = C_row + 20001;                                // 20,000
    int* C_src = C_wp + 20000;                                 // 320,000 (CSR-ordered src)
    float* C_ea = (float*)(C_src + 320000);                    // 320,000 (CSR-ordered ea)

    float* out_logits = (float*)d_out;
    float* out_h = out_logits + (size_t)N_NODES * 1000;

    int gatblk = (N_NODES + 3) / 4;
    int gemmM = (N_NODES + 127) / 128;   // 157
    dim3 gl(gemmM, 4);                   // old gemm, N=512 (merged xl|xr), K=32

    // 0. build CSR over dst (reused by both GAT layers)
    hipMemsetAsync(C_cnt, 0, (size_t)20000 * 4, stream);
    k_hist<<<(N_EDGES + 255) / 256, 256, 0, stream>>>(dst, C_cnt);
    k_scan<<<1, 1024, 0, stream>>>(C_cnt, C_row, C_wp, N_NODES);
    k_fill<<<(N_EDGES + 255) / 256, 256, 0, stream>>>(src, dst, ea, C_wp, C_src, C_ea);

    // 0b. all weight converts (swizzled for the K=256 LDS-resident GEMM)
    k_wcvt_all<<<(540672 + 255) / 256, 256, 0, stream>>>(
        Wl1, Wr1, W_down, Wl2, Wr2, W_up, W_cls,
        Wt_l1, Wt_r1, Wt_down, Wt_l2, Wt_r2, Wt_up, Wt_cls);

    // 1. h0 = x @ W_in + b_in (bf16)
    k_inproj<<<(N_NODES * 32 + 255) / 256, 256, 0, stream>>>(x_gnn, W_in, b_in, B_h0b);
    // 2. merged xl|xr = h0 @ [Wl1|Wr1]  (N=512, K=32 MFMA, bf16 out)
    k_gemm_bf16<<<gl, 256, 0, stream>>>(B_h0b, Wt_l1, nullptr, B_xlr, nullptr, N_NODES, 512, 32);
    // 3. GAT1 fused (+bias +LN) -> h1 (fp32 for residual) + bf16 act
    k_gat_ln<<<gatblk, 256, 0, stream>>>(C_row, C_src, C_ea, B_xlr, We1, att1,
                                         bg1, nullptr, ln1_g, ln1_b, B_h1, B_actb);
    // 4. z = LN(h1 @ W_down)  -- GEMM with fused LN
    k_gemm_ln<<<dim3(gemmM, 1), 256, 0, stream>>>(
        B_actb, Wt_down, N_NODES, 256, 256, nullptr, nullptr, lnd_g, lnd_b, B_z, B_actb);
    // 5. merged xl2|xr2 = z @ [Wl2|Wr2] (N=512) + GAT2 fused (+bias +res z +LN)
    k_gemm_ln<<<dim3(gemmM, 2), 256, 0, stream>>>(
        B_actb, Wt_l2, N_NODES, 512, 512, nullptr, nullptr, nullptr, nullptr, nullptr, B_xlr);
    k_gat_ln<<<gatblk, 256, 0, stream>>>(C_row, C_src, C_ea, B_xlr, We2, att2,
                                         bg2, B_z, ln2_g, ln2_b, nullptr, B_actb);
    // 6+7. h = LN(z2 @ W_up + h1) -> out_h (fp32) + bf16 act (fused GEMM+LN)
    k_gemm_ln<<<dim3(gemmM, 1), 256, 0, stream>>>(
        B_actb, Wt_up, N_NODES, 256, 256, nullptr, B_h1, lnu_g, lnu_b, out_h, B_actb);
    // 8. logits = h @ W_cls + b_cls  (N=1000, padded B image to 1024)
    k_gemm_ln<<<dim3(gemmM, 4), 256, 0, stream>>>(
        B_actb, Wt_cls, N_NODES, 1000, 1000, b_cls, nullptr, nullptr, nullptr,
        out_logits, nullptr);
}

// Round 5
// 430.065 us; speedup vs baseline: 1.1603x; 1.1603x over previous
//
#include <hip/hip_runtime.h>
#include <math.h>

#define N_NODES 20000
#define N_EDGES 320000

typedef __attribute__((ext_vector_type(8))) __bf16 bf16x8;
typedef __attribute__((ext_vector_type(8))) unsigned short ushort8;
typedef __attribute__((ext_vector_type(4))) float floatx4;

// ---- fp32 -> bf16 (RNE) raw bits ----
__device__ __forceinline__ unsigned short f2b(float f) {
    unsigned int u = __float_as_uint(f);
    unsigned int r = (u + 0x7fffu + ((u >> 16) & 1u)) >> 16;
    return (unsigned short)r;
}
// ---- bf16 bits -> fp32 ----
__device__ __forceinline__ float b2f(unsigned short u) {
    return __uint_as_float(((unsigned int)u) << 16);
}

// ---- in_proj: h0[N,32] = x[N,18] @ W[18,32] + b  (bf16 out) ----
__global__ void k_inproj(const float* __restrict__ x, const float* __restrict__ W,
                         const float* __restrict__ b, unsigned short* __restrict__ h0) {
    int t = blockIdx.x * blockDim.x + threadIdx.x;
    if (t >= N_NODES * 32) return;
    int n = t >> 5, p = t & 31;
    float acc = b[p];
    const float* xr = x + n * 18;
#pragma unroll
    for (int k = 0; k < 18; k++) acc = fmaf(xr[k], W[k * 32 + p], acc);
    h0[t] = f2b(acc);
}

// ---- merged weight convert+transpose: all 7 weights in one launch ----
// W[K][N] fp32 -> Wt[N][K] bf16.
// For the K=256 weights (used by the LDS-resident GEMM) the within-row k-chunks
// are XOR-swizzled (chunk' = chunk ^ (n&7), chunk = 16B = 8 bf16) so the GEMM
// can stage LDS with a pure linear copy and read fragments conflict-free.
// W_cls is padded to 1024 cols (zeros) so the N=1000 GEMM needs no stage guards.
__global__ void k_wcvt_all(const float* __restrict__ Wl1, const float* __restrict__ Wr1,
                           const float* __restrict__ Wdn, const float* __restrict__ Wl2,
                           const float* __restrict__ Wr2, const float* __restrict__ Wup,
                           const float* __restrict__ Wcl,
                           unsigned short* __restrict__ o1, unsigned short* __restrict__ o2,
                           unsigned short* __restrict__ o3, unsigned short* __restrict__ o4,
                           unsigned short* __restrict__ o5, unsigned short* __restrict__ o6,
                           unsigned short* __restrict__ o7) {
    int t = blockIdx.x * blockDim.x + threadIdx.x;
    const float* W; unsigned short* O; int Nd, K, idx; bool swz;
    if (t < 8192)        { W = Wl1; O = o1; Nd = 256;  K = 32;  idx = t;          swz = false; }
    else if (t < 16384)  { W = Wr1; O = o2; Nd = 256;  K = 32;  idx = t - 8192;   swz = false; }
    else if (t < 81920)  { W = Wdn; O = o3; Nd = 256;  K = 256; idx = t - 16384;  swz = true; }
    else if (t < 147456) { W = Wl2; O = o4; Nd = 256;  K = 256; idx = t - 81920;  swz = true; }
    else if (t < 212992) { W = Wr2; O = o5; Nd = 256;  K = 256; idx = t - 147456; swz = true; }
    else if (t < 278528) { W = Wup; O = o6; Nd = 256;  K = 256; idx = t - 212992; swz = true; }
    else if (t < 540672) { W = Wcl; O = o7; Nd = 1000; K = 256; idx = t - 278528; swz = true; }
    else return;
    int n = idx / K, k = idx % K;
    float v = (n < Nd) ? W[(size_t)k * Nd + n] : 0.f;   // pad rows -> 0
    int pos = swz ? (n * K + ((((k >> 3) ^ (n & 7)) << 3) | (k & 7))) : idx;
    O[pos] = f2b(v);
}

// ---- bf16 MFMA GEMM (generic, reg-staged): C[M,N] = A[M,K] @ Bt[N,K]^T
// kept only for the K=32 in-proj GEMM.
__global__ __launch_bounds__(256) void k_gemm_bf16(
    const unsigned short* __restrict__ A, const unsigned short* __restrict__ Bt,
    float* __restrict__ Cf, unsigned short* __restrict__ Cb,
    const float* __restrict__ bias, int M, int N, int K) {
    __shared__ unsigned short As[8 * 64 * 8];
    __shared__ unsigned short Bs[8 * 64 * 8];
    int tid = threadIdx.x;
    int wave = tid >> 6, lane = tid & 63;
    int wr = wave >> 1, wc = wave & 1;
    int row0 = blockIdx.x * 128, col0 = blockIdx.y * 128;
    floatx4 zero4 = {0.f, 0.f, 0.f, 0.f};
    floatx4 acc[4][4];
#pragma unroll
    for (int i = 0; i < 4; i++)
#pragma unroll
        for (int j = 0; j < 4; j++) acc[i][j] = zero4;
    for (int kb = 0; kb < K; kb += 32) {
#pragma unroll
        for (int q = 0; q < 2; q++) {
            int c = tid * 2 + q;           // 0..511
            int row = c >> 2, koff = (c & 3) * 8;
            int lp = (row & 15) + 16 * (koff >> 3);
            int mt = row >> 4;
            ushort8 va = {0, 0, 0, 0, 0, 0, 0, 0};
            if (row0 + row < M)
                va = *(const ushort8*)(A + (size_t)(row0 + row) * K + kb + koff);
            *(ushort8*)(As + (mt * 64 + lp) * 8) = va;
            ushort8 vb = {0, 0, 0, 0, 0, 0, 0, 0};
            if (col0 + row < N)
                vb = *(const ushort8*)(Bt + (size_t)(col0 + row) * K + kb + koff);
            *(ushort8*)(Bs + (mt * 64 + lp) * 8) = vb;
        }
        __syncthreads();
        bf16x8 af[4], bfr[4];
#pragma unroll
        for (int i = 0; i < 4; i++)
            af[i] = *(const bf16x8*)(As + ((wr * 4 + i) * 64 + lane) * 8);
#pragma unroll
        for (int j = 0; j < 4; j++)
            bfr[j] = *(const bf16x8*)(Bs + ((wc * 4 + j) * 64 + lane) * 8);
#pragma unroll
        for (int i = 0; i < 4; i++)
#pragma unroll
            for (int j = 0; j < 4; j++)
                acc[i][j] = __builtin_amdgcn_mfma_f32_16x16x32_bf16(
                    af[i], bfr[j], acc[i][j], 0, 0, 0);
        __syncthreads();
    }
    int quad = lane >> 4, nl = lane & 15;
#pragma unroll
    for (int i = 0; i < 4; i++) {
#pragma unroll
        for (int j = 0; j < 4; j++) {
            int col = col0 + wc * 64 + j * 16 + nl;
            if (col >= N) continue;
            float bv = bias ? bias[col] : 0.f;
#pragma unroll
            for (int r = 0; r < 4; r++) {
                int rr = row0 + wr * 64 + i * 16 + quad * 4 + r;
                if (rr >= M) continue;
                float v = acc[i][j][r] + bv;
                if (Cf) Cf[(size_t)rr * N + col] = v;
                else Cb[(size_t)rr * N + col] = f2b(v);
            }
        }
    }
}

// ---- K=256 GEMM with LDS-resident B panel + optional fused LayerNorm ----
// v2: occupancy-first retiling (round-4 post-mortem: 4 waves/CU = 8.5% occ).
// 1024 threads = 16 waves in a 4x4 grid; block tile 64 rows x 256 cols.
// Wave tile 16 rows x 64 cols: per K-step = 1 global A-load (prefetched one
// step ahead) + 4 LDS B-reads + 4 MFMAs, zero barriers in the K-loop.
// B-panel [256 cols][256 k] bf16 = 128 KB staged once (linear copy of the
// pre-swizzled weight image). 16 waves/CU = 4/SIMD hides A-load latency.
// Grid.x = 313 -> all 256 CUs busy (vs 157 at the old 128-row tile).
// Epilogue: optional bias, or fused LayerNorm (with optional fp32 residual).
__global__ __launch_bounds__(1024, 1) void k_gemm_ln(
    const unsigned short* __restrict__ A,    // [M][256] bf16
    const unsigned short* __restrict__ Bsw,  // [Npad][256] bf16, chunk-swizzled
    int M, int Ncols, int ldC,
    const float* __restrict__ bias,          // per-col bias or null
    const float* __restrict__ res,           // [M][256] fp32 residual (LN only) or null
    const float* __restrict__ g, const float* __restrict__ b,  // LN params or null
    float* __restrict__ outf, unsigned short* __restrict__ outb) {
    __shared__ unsigned short Bs[256 * 256];   // 128 KB B panel
    __shared__ float red[4][64][2];            // per-row (sum,sumsq) partial per wc
    int tid = threadIdx.x, lane = tid & 63, wave = tid >> 6;
    int wr = wave >> 2, wc = wave & 3;         // 4 row-waves x 4 col-waves
    int nl = lane & 15, quad = lane >> 4;
    int row0 = blockIdx.x * 64, col0 = blockIdx.y * 256;

    // A fragment: row = row0 + wr*16 + nl, k-chunk = quad*8 within each K-step
    const unsigned short* aptr =
        A + (size_t)(row0 + wr * 16 + nl) * 256 + quad * 8;
    bf16x8 a_cur, a_nxt;
    a_cur = *(const bf16x8*)(aptr);            // K-step 0 (overlaps B staging)
    a_nxt = a_cur;

    // stage B panel: linear 128 KB copy (8192 ushort8 / 1024 threads = 8 iters)
    {
        const ushort8* bsrc8 = (const ushort8*)(Bsw + (size_t)col0 * 256);
        ushort8* bdst8 = (ushort8*)Bs;
#pragma unroll
        for (int t = 0; t < 8; t++) bdst8[t * 1024 + tid] = bsrc8[t * 1024 + tid];
    }
    __syncthreads();

    floatx4 zero4 = {0.f, 0.f, 0.f, 0.f};
    floatx4 acc[4];
#pragma unroll
    for (int j = 0; j < 4; j++) acc[j] = zero4;

    int swx = nl & 7;                          // col&7 (wc*64, j*16 are mult of 8)
#pragma unroll
    for (int kb = 0; kb < 8; kb++) {
        if (kb < 7) a_nxt = *(const bf16x8*)(aptr + (kb + 1) * 32);
        int kq = kb * 4 + quad;
#pragma unroll
        for (int j = 0; j < 4; j++) {
            int c = wc * 64 + j * 16 + nl;     // local B col
            bf16x8 bf = *(const bf16x8*)((const char*)Bs +
                                         (size_t)c * 512 + ((kq ^ swx) << 4));
            acc[j] = __builtin_amdgcn_mfma_f32_16x16x32_bf16(a_cur, bf, acc[j], 0, 0, 0);
        }
        a_cur = a_nxt;
    }

    if (g == nullptr) {
        // plain epilogue: optional bias, guarded stores
#pragma unroll
        for (int j = 0; j < 4; j++) {
            int col = col0 + wc * 64 + j * 16 + nl;
            if (col >= Ncols) continue;
            float bv = bias ? bias[col] : 0.f;
#pragma unroll
            for (int r = 0; r < 4; r++) {
                int rr = row0 + wr * 16 + quad * 4 + r;
                if (rr >= M) continue;
                float v = acc[j][r] + bv;
                if (outf) outf[(size_t)rr * ldC + col] = v;
                if (outb) outb[(size_t)rr * ldC + col] = f2b(v);
            }
        }
        return;
    }

    // ---- fused LayerNorm epilogue (Ncols == 256, ldC == 256) ----
    if (res) {
#pragma unroll
        for (int j = 0; j < 4; j++) {
            int col = wc * 64 + j * 16 + nl;
#pragma unroll
            for (int r = 0; r < 4; r++) {
                int rr = row0 + wr * 16 + quad * 4 + r;
                acc[j][r] += res[(size_t)rr * 256 + col];
            }
        }
    }
    // per-row partials over this wave's 64 cols (reduce across nl within quad group)
#pragma unroll
    for (int r = 0; r < 4; r++) {
        float s = 0.f, q = 0.f;
#pragma unroll
        for (int j = 0; j < 4; j++) {
            float v = acc[j][r];
            s += v;
            q = fmaf(v, v, q);
        }
        s += __shfl_xor(s, 1, 64); q += __shfl_xor(q, 1, 64);
        s += __shfl_xor(s, 2, 64); q += __shfl_xor(q, 2, 64);
        s += __shfl_xor(s, 4, 64); q += __shfl_xor(q, 4, 64);
        s += __shfl_xor(s, 8, 64); q += __shfl_xor(q, 8, 64);
        if (nl == 0) {
            int lr = wr * 16 + quad * 4 + r;
            red[wc][lr][0] = s;
            red[wc][lr][1] = q;
        }
    }
    __syncthreads();
    float mean_[4], rstd_[4];
#pragma unroll
    for (int r = 0; r < 4; r++) {
        int lr = wr * 16 + quad * 4 + r;
        float sum = red[0][lr][0] + red[1][lr][0] + red[2][lr][0] + red[3][lr][0];
        float sq  = red[0][lr][1] + red[1][lr][1] + red[2][lr][1] + red[3][lr][1];
        float mean = sum * (1.0f / 256.0f);
        float var = sq * (1.0f / 256.0f) - mean * mean;
        mean_[r] = mean;
        rstd_[r] = 1.0f / sqrtf(var + 1e-5f);
    }
#pragma unroll
    for (int j = 0; j < 4; j++) {
        int col = wc * 64 + j * 16 + nl;
        float gv = g[col], bvv = b[col];
#pragma unroll
        for (int r = 0; r < 4; r++) {
            int rr = row0 + wr * 16 + quad * 4 + r;
            if (rr >= M) continue;
            float o = (acc[j][r] - mean_[r]) * rstd_[r] * gv + bvv;
            if (outf) outf[(size_t)rr * 256 + col] = o;
            if (outb) outb[(size_t)rr * 256 + col] = f2b(o);
        }
    }
}

// ---- CSR build: histogram of dst ----
__global__ void k_hist(const int* __restrict__ dst, int* __restrict__ cnt) {
    int e = blockIdx.x * blockDim.x + threadIdx.x;
    if (e >= N_EDGES) return;
    atomicAdd(cnt + dst[e], 1);
}

// ---- CSR build: fast single-block scan (1024 threads, 20 elems/thread) ----
__global__ __launch_bounds__(1024) void k_scan(const int* __restrict__ cnt,
                                               int* __restrict__ rowptr,
                                               int* __restrict__ wp, int n) {
    __shared__ int tsum[1024];
    int t = threadIdx.x;
    const int chunk = 20;  // 1024*20 = 20480 >= 20000
    int i0 = t * chunk;
    int local[chunk];
    int s = 0;
#pragma unroll
    for (int j = 0; j < chunk; j++) {
        int i = i0 + j;
        int v = (i < n) ? cnt[i] : 0;
        local[j] = s;  // exclusive prefix within chunk
        s += v;
    }
    tsum[t] = s;
    __syncthreads();
    // inclusive Hillis-Steele scan over 1024 partials
    for (int off = 1; off < 1024; off <<= 1) {
        int other = (t >= off) ? tsum[t - off] : 0;
        __syncthreads();
        tsum[t] += other;
        __syncthreads();
    }
    int base = (t > 0) ? tsum[t - 1] : 0;
#pragma unroll
    for (int j = 0; j < chunk; j++) {
        int i = i0 + j;
        if (i < n) {
            int ex = base + local[j];
            rowptr[i] = ex;
            wp[i] = ex;
        }
    }
    if (t == 1023) rowptr[n] = tsum[1023];
}

// ---- CSR build: scatter src id + edge attr into CSR order ----
__global__ void k_fill(const int* __restrict__ src, const int* __restrict__ dst,
                       const float* __restrict__ ea, int* __restrict__ wp,
                       int* __restrict__ srcs, float* __restrict__ eas) {
    int e = blockIdx.x * blockDim.x + threadIdx.x;
    if (e >= N_EDGES) return;
    int p = atomicAdd(wp + dst[e], 1);
    srcs[p] = src[e];
    eas[p] = ea[e];
}

// ---- fused GATv2 edge phase + LayerNorm epilogue
// wave per dst node, online softmax, 2 edges/iteration.
// Edge metadata (srcs/eas) is CSR-ordered -> sequential loads, no indirection.
// Row gathers are kept 3 pairs (6 edges) in flight to cover LLC/HBM latency.
// xlr: [N][512] bf16 where cols 0..255 = x@Wl, 256..511 = x@Wr
// epilogue: o = agg + vbias (+res) ; LN(o; g,b) -> outf (fp32) / outb (bf16)
__global__ __launch_bounds__(256) void k_gat_ln(
    const int* __restrict__ rowptr, const int* __restrict__ srcs,
    const float* __restrict__ eas, const unsigned short* __restrict__ xlr,
    const float* __restrict__ We, const float* __restrict__ att,
    const float* __restrict__ vbias, const float* __restrict__ res,
    const float* __restrict__ g, const float* __restrict__ b,
    float* __restrict__ outf, unsigned short* __restrict__ outb) {
    int node = blockIdx.x * 4 + (threadIdx.x >> 6);
    if (node >= N_NODES) return;
    int lane = threadIdx.x & 63;  // lane covers dims [4*lane, 4*lane+4)
    int beg = rowptr[node], end = rowptr[node + 1];
    float4 wv = ((const float4*)We)[lane];
    float4 av = ((const float4*)att)[lane];
    ushort4 xru = ((const ushort4*)(xlr + (size_t)node * 512 + 256))[lane];
    float4 rv = make_float4(b2f(xru.x), b2f(xru.y), b2f(xru.z), b2f(xru.w));
    float m = -3.0e38f, l = 0.f;
    float4 acc = make_float4(0.f, 0.f, 0.f, 0.f);
    if (beg < end) {
        int last = end - 1;
        int i1 = (beg + 1 < end) ? beg + 1 : last;
        int i2 = (beg + 2 < end) ? beg + 2 : last;
        int i3 = (beg + 3 < end) ? beg + 3 : last;
        int i4 = (beg + 4 < end) ? beg + 4 : last;
        int i5 = (beg + 5 < end) ? beg + 5 : last;
        int i6 = (beg + 6 < end) ? beg + 6 : last;
        int i7 = (beg + 7 < end) ? beg + 7 : last;
        int s0a = srcs[beg], s0b = srcs[i1];
        int s1a = srcs[i2],  s1b = srcs[i3];
        int s2a = srcs[i4],  s2b = srcs[i5];
        int s3a = srcs[i6],  s3b = srcs[i7];
        float a0a = eas[beg], a0b = eas[i1];
        float a1a = eas[i2],  a1b = eas[i3];
        float a2a = eas[i4],  a2b = eas[i5];
        float a3a = eas[i6],  a3b = eas[i7];
        ushort4 x0a = ((const ushort4*)(xlr + (size_t)s0a * 512))[lane];
        ushort4 x0b = ((const ushort4*)(xlr + (size_t)s0b * 512))[lane];
        ushort4 x1a = ((const ushort4*)(xlr + (size_t)s1a * 512))[lane];
        ushort4 x1b = ((const ushort4*)(xlr + (size_t)s1b * 512))[lane];
        ushort4 x2a = ((const ushort4*)(xlr + (size_t)s2a * 512))[lane];
        ushort4 x2b = ((const ushort4*)(xlr + (size_t)s2b * 512))[lane];
        for (int i = beg; i < end; i += 2) {
            int j8 = (i + 8 < end) ? i + 8 : last;
            int j9 = (i + 9 < end) ? i + 9 : last;
            int s4a = srcs[j8], s4b = srcs[j9];
            float a4a = eas[j8], a4b = eas[j9];
            ushort4 x3a = ((const ushort4*)(xlr + (size_t)s3a * 512))[lane];
            ushort4 x3b = ((const ushort4*)(xlr + (size_t)s3b * 512))[lane];
            float4 lva = make_float4(b2f(x0a.x), b2f(x0a.y), b2f(x0a.z), b2f(x0a.w));
            float4 lvb = make_float4(b2f(x0b.x), b2f(x0b.y), b2f(x0b.z), b2f(x0b.w));
            float f, pa = 0.f, pb = 0.f;
            f = lva.x + rv.x + a0a * wv.x; f = fmaxf(f, 0.2f * f); pa = fmaf(f, av.x, pa);
            f = lva.y + rv.y + a0a * wv.y; f = fmaxf(f, 0.2f * f); pa = fmaf(f, av.y, pa);
            f = lva.z + rv.z + a0a * wv.z; f = fmaxf(f, 0.2f * f); pa = fmaf(f, av.z, pa);
            f = lva.w + rv.w + a0a * wv.w; f = fmaxf(f, 0.2f * f); pa = fmaf(f, av.w, pa);
            f = lvb.x + rv.x + a0b * wv.x; f = fmaxf(f, 0.2f * f); pb = fmaf(f, av.x, pb);
            f = lvb.y + rv.y + a0b * wv.y; f = fmaxf(f, 0.2f * f); pb = fmaf(f, av.y, pb);
            f = lvb.z + rv.z + a0b * wv.z; f = fmaxf(f, 0.2f * f); pb = fmaf(f, av.z, pb);
            f = lvb.w + rv.w + a0b * wv.w; f = fmaxf(f, 0.2f * f); pb = fmaf(f, av.w, pb);
            pa += __shfl_xor(pa, 1, 64);
            pa += __shfl_xor(pa, 2, 64);
            pa += __shfl_xor(pa, 4, 64);
            pb += __shfl_xor(pb, 1, 64);
            pb += __shfl_xor(pb, 2, 64);
            pb += __shfl_xor(pb, 4, 64);
            if (i + 1 >= end) pb = -3.0e38f;  // odd tail: second edge is a dummy
            float mnew = fmaxf(fmaxf(m, pa), pb);
            float scale = __expf(m - mnew);
            float wa = __expf(pa - mnew);
            float wb = __expf(pb - mnew);
            acc.x = fmaf(acc.x, scale, fmaf(wa, lva.x, wb * lvb.x));
            acc.y = fmaf(acc.y, scale, fmaf(wa, lva.y, wb * lvb.y));
            acc.z = fmaf(acc.z, scale, fmaf(wa, lva.z, wb * lvb.z));
            acc.w = fmaf(acc.w, scale, fmaf(wa, lva.w, wb * lvb.w));
            l = fmaf(l, scale, wa + wb);
            m = mnew;
            x0a = x1a; x0b = x1b; x1a = x2a; x1b = x2b; x2a = x3a; x2b = x3b;
            a0a = a1a; a0b = a1b; a1a = a2a; a1b = a2b; a2a = a3a; a2b = a3b;
            a3a = a4a; a3b = a4b; s3a = s4a; s3b = s4b;
        }
    }
    float inv = 1.0f / (l + 1e-16f);
    float4 vb4 = ((const float4*)vbias)[lane];
    float4 o = make_float4(fmaf(acc.x, inv, vb4.x), fmaf(acc.y, inv, vb4.y),
                           fmaf(acc.z, inv, vb4.z), fmaf(acc.w, inv, vb4.w));
    if (res) {
        float4 r4 = ((const float4*)(res + (size_t)node * 256))[lane];
        o.x += r4.x; o.y += r4.y; o.z += r4.z; o.w += r4.w;
    }
    float sum = o.x + o.y + o.z + o.w;
#pragma unroll
    for (int off = 32; off > 0; off >>= 1) sum += __shfl_xor(sum, off, 64);
    float mean = sum * (1.0f / 256.0f);
    float dx = o.x - mean, dy = o.y - mean, dz = o.z - mean, dw = o.w - mean;
    float sq = dx * dx + dy * dy + dz * dz + dw * dw;
#pragma unroll
    for (int off = 32; off > 0; off >>= 1) sq += __shfl_xor(sq, off, 64);
    float rstd = 1.0f / sqrtf(sq * (1.0f / 256.0f) + 1e-5f);
    float4 gg = ((const float4*)g)[lane];
    float4 bb = ((const float4*)b)[lane];
    float4 o4 = make_float4(dx * rstd * gg.x + bb.x, dy * rstd * gg.y + bb.y,
                            dz * rstd * gg.z + bb.z, dw * rstd * gg.w + bb.w);
    if (outf) ((float4*)(outf + (size_t)node * 256))[lane] = o4;
    if (outb) {
        ushort4 u;
        u.x = f2b(o4.x); u.y = f2b(o4.y); u.z = f2b(o4.z); u.w = f2b(o4.w);
        ((ushort4*)(outb + (size_t)node * 256))[lane] = u;
    }
}

extern "C" void kernel_launch(void* const* d_in, const int* in_sizes, int n_in,
                              void* d_out, int out_size, void* d_ws, size_t ws_size,
                              hipStream_t stream) {
    const float* x_gnn = (const float*)d_in[0];
    const int* ei = (const int*)d_in[1];
    const int* src = ei;
    const int* dst = ei + N_EDGES;
    const float* ea   = (const float*)d_in[2];
    const float* W_in = (const float*)d_in[3];
    const float* b_in = (const float*)d_in[4];
    const float* Wl1  = (const float*)d_in[5];
    const float* Wr1  = (const float*)d_in[6];
    const float* We1  = (const float*)d_in[7];
    const float* att1 = (const float*)d_in[8];
    const float* bg1  = (const float*)d_in[9];
    const float* ln1_g = (const float*)d_in[10];
    const float* ln1_b = (const float*)d_in[11];
    const float* W_down = (const float*)d_in[12];
    const float* lnd_g = (const float*)d_in[13];
    const float* lnd_b = (const float*)d_in[14];
    const float* Wl2  = (const float*)d_in[15];
    const float* Wr2  = (const float*)d_in[16];
    const float* We2  = (const float*)d_in[17];
    const float* att2 = (const float*)d_in[18];
    const float* bg2  = (const float*)d_in[19];
    const float* ln2_g = (const float*)d_in[20];
    const float* ln2_b = (const float*)d_in[21];
    const float* W_up = (const float*)d_in[22];
    const float* lnu_g = (const float*)d_in[23];
    const float* lnu_b = (const float*)d_in[24];
    const float* W_cls = (const float*)d_in[25];
    const float* b_cls = (const float*)d_in[26];

    // ---- workspace layout ----
    float* ws = (float*)d_ws;
    float* B_agg = ws;                                // 5,120,000 f (unused, kept for layout)
    float* B_h1  = B_agg + 5120000;                   // 5,120,000 f
    float* B_z   = B_h1 + 5120000;                    // 5,120,000 f
    unsigned short* B_xlr = (unsigned short*)(B_z + 5120000);  // 10,240,000 us ([N][512])
    unsigned short* B_actb = B_xlr + 10240000;                 // 5,120,000 us
    unsigned short* B_h0b = B_actb + 5120000;                  // 640,000 us
    unsigned short* Wt_l1 = B_h0b + 640000;                    // 8,192  ([512][32] with Wt_r1)
    unsigned short* Wt_r1 = Wt_l1 + 8192;                      // 8,192
    unsigned short* Wt_down = Wt_r1 + 8192;                    // 65,536 (swizzled)
    unsigned short* Wt_l2 = Wt_down + 65536;                   // ([512][256] with Wt_r2, swz)
    unsigned short* Wt_r2 = Wt_l2 + 65536;
    unsigned short* Wt_up = Wt_r2 + 65536;                     // 65,536 (swz)
    unsigned short* Wt_cls = Wt_up + 65536;                    // 262,144 ([1024][256], swz, pad)
    int* C_cnt = (int*)(Wt_cls + 262144);                      // 20,000
    int* C_row = C_cnt + 20000;                                // 20,001
    int* C_wp  = C_row + 20001;                                // 20,000
    int* C_src = C_wp + 20000;                                 // 320,000 (CSR-ordered src)
    float* C_ea = (float*)(C_src + 320000);                    // 320,000 (CSR-ordered ea)

    float* out_logits = (float*)d_out;
    float* out_h = out_logits + (size_t)N_NODES * 1000;

    int gatblk = (N_NODES + 3) / 4;
    int gemmM64 = (N_NODES + 63) / 64;   // 313 (64-row tiles for k_gemm_ln)
    dim3 gl((N_NODES + 127) / 128, 4);   // old gemm, N=512 (merged xl|xr), K=32

    // 0. build CSR over dst (reused by both GAT layers)
    hipMemsetAsync(C_cnt, 0, (size_t)20000 * 4, stream);
    k_hist<<<(N_EDGES + 255) / 256, 256, 0, stream>>>(dst, C_cnt);
    k_scan<<<1, 1024, 0, stream>>>(C_cnt, C_row, C_wp, N_NODES);
    k_fill<<<(N_EDGES + 255) / 256, 256, 0, stream>>>(src, dst, ea, C_wp, C_src, C_ea);

    // 0b. all weight converts (swizzled for the K=256 LDS-resident GEMM)
    k_wcvt_all<<<(540672 + 255) / 256, 256, 0, stream>>>(
        Wl1, Wr1, W_down, Wl2, Wr2, W_up, W_cls,
        Wt_l1, Wt_r1, Wt_down, Wt_l2, Wt_r2, Wt_up, Wt_cls);

    // 1. h0 = x @ W_in + b_in (bf16)
    k_inproj<<<(N_NODES * 32 + 255) / 256, 256, 0, stream>>>(x_gnn, W_in, b_in, B_h0b);
    // 2. merged xl|xr = h0 @ [Wl1|Wr1]  (N=512, K=32 MFMA, bf16 out)
    k_gemm_bf16<<<gl, 256, 0, stream>>>(B_h0b, Wt_l1, nullptr, B_xlr, nullptr, N_NODES, 512, 32);
    // 3. GAT1 fused (+bias +LN) -> h1 (fp32 for residual) + bf16 act
    k_gat_ln<<<gatblk, 256, 0, stream>>>(C_row, C_src, C_ea, B_xlr, We1, att1,
                                         bg1, nullptr, ln1_g, ln1_b, B_h1, B_actb);
    // 4. z = LN(h1 @ W_down)  -- GEMM with fused LN
    k_gemm_ln<<<dim3(gemmM64, 1), 1024, 0, stream>>>(
        B_actb, Wt_down, N_NODES, 256, 256, nullptr, nullptr, lnd_g, lnd_b, B_z, B_actb);
    // 5. merged xl2|xr2 = z @ [Wl2|Wr2] (N=512) + GAT2 fused (+bias +res z +LN)
    k_gemm_ln<<<dim3(gemmM64, 2), 1024, 0, stream>>>(
        B_actb, Wt_l2, N_NODES, 512, 512, nullptr, nullptr, nullptr, nullptr, nullptr, B_xlr);
    k_gat_ln<<<gatblk, 256, 0, stream>>>(C_row, C_src, C_ea, B_xlr, We2, att2,
                                         bg2, B_z, ln2_g, ln2_b, nullptr, B_actb);
    // 6+7. h = LN(z2 @ W_up + h1) -> out_h (fp32) + bf16 act (fused GEMM+LN)
    k_gemm_ln<<<dim3(gemmM64, 1), 1024, 0, stream>>>(
        B_actb, Wt_up, N_NODES, 256, 256, nullptr, B_h1, lnu_g, lnu_b, out_h, B_actb);
    // 8. logits = h @ W_cls + b_cls  (N=1000, padded B image to 1024)
    k_gemm_ln<<<dim3(gemmM64, 4), 1024, 0, stream>>>(
        B_actb, Wt_cls, N_NODES, 1000, 1000, b_cls, nullptr, nullptr, nullptr,
        out_logits, nullptr);
}